// Round 7
// baseline (5527.361 us; speedup 1.0000x reference)
//
#include <hip/hip_runtime.h>
#include <hip/hip_bf16.h>

#define V_ 100000
#define E_ 100
#define H_ 100
#define T_ 25
#define B_ 256
#define S_ 512

using u16 = unsigned short;
using u32 = unsigned int;
using u64 = unsigned long long;
typedef __attribute__((ext_vector_type(8))) short short8;
typedef __attribute__((ext_vector_type(4))) float f32x4;

__device__ __forceinline__ float bf2f(u16 v){
  u32 x = ((u32)v) << 16;
  return __builtin_bit_cast(float, x);
}
__device__ __forceinline__ u16 f2bf(float f){
  u32 x = __builtin_bit_cast(u32, f);
  u32 r = (x + 0x7FFFu + ((x >> 16) & 1u)) >> 16;  // RNE
  return (u16)r;
}
__device__ __forceinline__ float sigf(float x){
  return __builtin_amdgcn_rcpf(1.0f + __builtin_amdgcn_exp2f(-1.4426950408889634f * x));
}
__device__ __forceinline__ float tanh_fast(float x){
  return 1.0f - 2.0f * __builtin_amdgcn_rcpf(1.0f + __builtin_amdgcn_exp2f(2.8853900817779268f * x));
}
__device__ __forceinline__ float bcast(float v, int l){
  return __builtin_bit_cast(float, __builtin_amdgcn_readlane(__builtin_bit_cast(int, v), l));
}
// 256B-row XOR swizzle: byte ^= ((row&7)<<4); involution, preserves 16B chunks
__device__ __forceinline__ int hswz(int a){ return a ^ (((a >> 8) & 7) << 4); }

// LDS-visibility-only barrier (no vmcnt drain)
#define BAR() asm volatile("s_waitcnt lgkmcnt(0)\n\ts_barrier" ::: "memory")

// ---------------------------------------------------------------------------
// prep: xg gather/cvt (blocks 0..16383) + wpad build (blocks 16384..17279).
// xg[s*256+b][128] bf16 = embed row (zero-padded k>=100).
// wpad[dir][448][256] bf16: rows g*112+j; cols 0..99 = w_ih, 128..227 = w_hh.
// ---------------------------------------------------------------------------
__global__ __launch_bounds__(256) void prep_kernel(
    const int* __restrict__ sent, const float* __restrict__ tab,
    const float* __restrict__ w_ih_f, const float* __restrict__ w_hh_f,
    const float* __restrict__ w_ih_b, const float* __restrict__ w_hh_b,
    u16* __restrict__ xg, u16* __restrict__ wpad)
{
  int bid = blockIdx.x;
  if (bid < 16384){
    int tid = bid * 256 + threadIdx.x;      // 131072*32
    int srow = tid >> 5, kb = tid & 31;
    int s = srow >> 8, b = srow & 255;
    int k0 = kb * 4;
    u64 out = 0;
    if (k0 < 100){
      int idx = sent[b * S_ + s];
      float4 v = *(const float4*)(tab + (size_t)idx * 100 + k0);
      out = (u64)f2bf(v.x) | ((u64)f2bf(v.y) << 16)
          | ((u64)f2bf(v.z) << 32) | ((u64)f2bf(v.w) << 48);
    }
    ((u64*)xg)[tid] = out;
  } else {
    int tid = (bid - 16384) * 256 + threadIdx.x;   // 2*448*256
    int dir = tid / (448 * 256);
    int rem = tid % (448 * 256);
    int np = rem >> 8, k = rem & 255;
    int g = np / 112, j = np % 112;
    float v = 0.f;
    if (j < 100){
      int n = g * 100 + j;
      if (k < 100)                    v = (dir ? w_ih_b : w_ih_f)[n * 100 + k];
      else if (k >= 128 && k < 228)   v = (dir ? w_hh_b : w_hh_f)[n * 100 + (k - 128)];
    }
    wpad[tid] = f2bf(v);
  }
}

// ---------------------------------------------------------------------------
// Fused BiLSTM. block = bb (16-batch group); 896 thr = 14 waves = TWO chains:
// waves 0-6 forward dir, waves 7-13 backward dir. The two independent
// recurrences co-resident on the same SIMDs fill each other's dependency
// stalls. Per chain: gates^T = Wpad[448][256] . [x;h][256][16] via
// mfma_16x16x32_bf16; acc(k+1) = bias + Wx.x(k+1) hoisted after nonlin(k)
// (off critical path, runs at setprio 0); h double-buffered in swizzled LDS.
// ---------------------------------------------------------------------------
__global__ __launch_bounds__(896, 1) void lstm_kernel(
    const u16* __restrict__ xg, const u16* __restrict__ wpad,
    const float* __restrict__ b_ih_f, const float* __restrict__ b_hh_f,
    const float* __restrict__ b_ih_b, const float* __restrict__ b_hh_b,
    u16* __restrict__ hbuf)
{
  int bb = blockIdx.x;
  int t = threadIdx.x;
  int cid = (t >= 448) ? 1 : 0;              // chain = direction
  int tl = t - cid * 448;
  int w = tl >> 6, l = tl & 63;
  int m = l & 15, ql = l >> 4;
  int j0 = w * 16 + ql * 4;
  bool jv = j0 < 100;
  int dir = cid;

  __shared__ __align__(16) char ha[2][2][4096];  // [chain][buf] h[16][128] bf16 swz

  for (int i = t; i < 4096; i += 896) ((u32*)(&ha[0][0][0]))[i] = 0;

  // loop-invariant W fragments
  short8 bf[4][8];
  {
    const u16* wb = wpad + (size_t)dir * 448 * 256;
#pragma unroll
    for (int g = 0; g < 4; g++)
#pragma unroll
      for (int ks = 0; ks < 8; ks++)
        bf[g][ks] = *(const short8*)(wb + (g * 112 + w * 16 + m) * 256 + ks * 32 + ql * 8);
  }
  // bias folded into MFMA C-init
  f32x4 bias4[4];
#pragma unroll
  for (int g = 0; g < 4; g++) bias4[g] = (f32x4){0.f, 0.f, 0.f, 0.f};
  if (jv){
    const float* bi = dir ? b_ih_b : b_ih_f;
    const float* bh = dir ? b_hh_b : b_hh_f;
#pragma unroll
    for (int g = 0; g < 4; g++)
#pragma unroll
      for (int r = 0; r < 4; r++)
        bias4[g][r] = bi[g * 100 + j0 + r] + bh[g * 100 + j0 + r];
  }

  float c[4] = {0.f, 0.f, 0.f, 0.f};
  int s0 = dir ? (S_ - 1) : 0, sd = dir ? -1 : 1;

  const u16* xbase = xg + ((size_t)(bb * 16 + m)) * 128 + ql * 8;
  const int XSTRIDE = 256 * 128;                 // elems per s

  // prologue: x(0), x(1) in regs; accA = bias + Wx.x(0)
  short8 xc0[4], xc1[4];
#pragma unroll
  for (int ks = 0; ks < 4; ks++){
    xc0[ks] = *(const short8*)(xbase + (size_t)s0 * XSTRIDE + ks * 32);
    xc1[ks] = *(const short8*)(xbase + (size_t)(s0 + sd) * XSTRIDE + ks * 32);
  }
  f32x4 accA[4], accB[4];
#pragma unroll
  for (int g = 0; g < 4; g++){
    accA[g] = __builtin_amdgcn_mfma_f32_16x16x32_bf16(bf[g][0], xc0[0], bias4[g], 0, 0, 0);
#pragma unroll
    for (int ks = 1; ks < 4; ks++)
      accA[g] = __builtin_amdgcn_mfma_f32_16x16x32_bf16(bf[g][ks], xc0[ks], accA[g], 0, 0, 0);
  }

  u16* hout = hbuf + ((size_t)(s0 * B_ + bb * 16 + m)) * 200 + dir * 100 + j0;
  const long hstride = (long)sd * B_ * 200;
  int kcur = 0;

  __syncthreads();

  // Step body: ACC holds bias+Wx.x(kcur); XN = x(kcur+1) frags; XL gets x(kcur+2);
  // AOUT = bias+Wx.x(kcur+1) for next step.  KODD = kcur&1 (static).
#define STEP(KODD, ACC, XN, AOUT, XL) do {                                     \
    __builtin_amdgcn_s_setprio(1);                                             \
    const char* hp_ = &ha[cid][(KODD) ^ 1][0];                                 \
    short8 hf_[4];                                                             \
    _Pragma("unroll")                                                          \
    for (int ks = 0; ks < 4; ks++)                                             \
      hf_[ks] = *(const short8*)(hp_ + hswz(m * 256 + ks * 64 + ql * 16));     \
    _Pragma("unroll")                                                          \
    for (int g = 0; g < 4; g++)                                                \
      _Pragma("unroll")                                                        \
      for (int ks = 0; ks < 4; ks++)                                           \
        ACC[g] = __builtin_amdgcn_mfma_f32_16x16x32_bf16(bf[g][4 + ks], hf_[ks], ACC[g], 0, 0, 0); \
    { int kk = kcur + 2; if (kk > S_ - 1) kk = S_ - 1;                         \
      const u16* xp_ = xbase + (size_t)(s0 + sd * kk) * XSTRIDE;               \
      _Pragma("unroll")                                                        \
      for (int ks = 0; ks < 4; ks++) XL[ks] = *(const short8*)(xp_ + ks * 32); }\
    if (jv){                                                                   \
      u64 pk = 0;                                                              \
      _Pragma("unroll")                                                        \
      for (int r = 0; r < 4; r++){                                             \
        float gi = sigf(ACC[0][r]);                                            \
        float gf = sigf(ACC[1][r]);                                            \
        float gg = tanh_fast(ACC[2][r]);                                       \
        float go = sigf(ACC[3][r]);                                            \
        c[r] = gf * c[r] + gi * gg;                                            \
        float h = go * tanh_fast(c[r]);                                        \
        pk |= ((u64)f2bf(h)) << (16 * r);                                      \
      }                                                                        \
      *(u64*)(&ha[cid][KODD][0] + hswz(m * 256 + j0 * 2)) = pk;                \
      *(u64*)hout = pk;                                                        \
    }                                                                          \
    hout += hstride;                                                           \
    __builtin_amdgcn_s_setprio(0);                                             \
    _Pragma("unroll")                                                          \
    for (int g = 0; g < 4; g++){                                               \
      AOUT[g] = __builtin_amdgcn_mfma_f32_16x16x32_bf16(bf[g][0], XN[0], bias4[g], 0, 0, 0); \
      _Pragma("unroll")                                                        \
      for (int ks = 1; ks < 4; ks++)                                           \
        AOUT[g] = __builtin_amdgcn_mfma_f32_16x16x32_bf16(bf[g][ks], XN[ks], AOUT[g], 0, 0, 0); \
    }                                                                          \
    BAR();                                                                     \
    kcur++;                                                                    \
  } while (0)

  for (int it = 0; it < S_ / 2; ++it){
    STEP(0, accA, xc1, accB, xc0);
    STEP(1, accB, xc0, accA, xc1);
  }
#undef STEP
}

// ---------------------------------------------------------------------------
// emissions = [hf,hb] @ w_out^T + b_out.  w_out staged in LDS.
// ---------------------------------------------------------------------------
__global__ __launch_bounds__(256) void emis_kernel(
    const u16* __restrict__ hbuf, const float* __restrict__ w_out,
    const float* __restrict__ b_out, float* __restrict__ em)
{
  __shared__ float wsm[T_ * 200];
  int t = threadIdx.x;
  for (int i = t; i < T_ * 200; i += 256) wsm[i] = w_out[i];
  __syncthreads();

  int tid = blockIdx.x * 256 + t;   // s*B + b
  uint4 hr[25];
  const uint4* hp = (const uint4*)(hbuf + (size_t)tid * 200);
#pragma unroll
  for (int i = 0; i < 25; i++) hr[i] = hp[i];
  float* out = em + (size_t)tid * T_;
  for (int tt = 0; tt < T_; ++tt){
    const float* wr = wsm + tt * 200;
    float acc = b_out[tt];
#pragma unroll
    for (int i = 0; i < 25; i++){
      u32 q0 = hr[i].x, q1 = hr[i].y, q2 = hr[i].z, q3 = hr[i].w;
      float f;
      f = __builtin_bit_cast(float, q0 << 16);         acc += f * wr[i*8+0];
      f = __builtin_bit_cast(float, q0 & 0xFFFF0000u); acc += f * wr[i*8+1];
      f = __builtin_bit_cast(float, q1 << 16);         acc += f * wr[i*8+2];
      f = __builtin_bit_cast(float, q1 & 0xFFFF0000u); acc += f * wr[i*8+3];
      f = __builtin_bit_cast(float, q2 << 16);         acc += f * wr[i*8+4];
      f = __builtin_bit_cast(float, q2 & 0xFFFF0000u); acc += f * wr[i*8+5];
      f = __builtin_bit_cast(float, q3 << 16);         acc += f * wr[i*8+6];
      f = __builtin_bit_cast(float, q3 & 0xFFFF0000u); acc += f * wr[i*8+7];
    }
    out[tt] = acc;
  }
}

// ---------------------------------------------------------------------------
// CRF: wave 0 = logZ scan, wave 1 = gold score.  diff[b] = logZ[b]-num[b].
// logZ scan uses base-2 score tracking (score_k = log2e*score) with the
// lane's OWN previous score as the exp2 anchor (args bounded: |k*spread|
// ~<= 12 << 127) -> no 25-wide max tree per step.
// ---------------------------------------------------------------------------
__global__ __launch_bounds__(128) void logznum_kernel(
    const float* __restrict__ em, const int* __restrict__ tags,
    const float* __restrict__ start_t, const float* __restrict__ end_t,
    const float* __restrict__ trans, float* __restrict__ diff)
{
  int b = blockIdx.x, t = threadIdx.x;
  __shared__ float tr_s[T_ * T_];
  __shared__ float res[2];
  for (int i = t; i < T_ * T_; i += 128) tr_s[i] = trans[i];
  __syncthreads();
  const float K  = 1.4426950408889634f;    // log2(e)
  const float LN2 = 0.69314718055994531f;

  if (t < 64){
    int lane = t;
    bool act = lane < T_;
    int ll = act ? lane : 0;
    float trc_k[T_];
#pragma unroll
    for (int tt = 0; tt < T_; tt++) trc_k[tt] = K * tr_s[tt * T_ + ll];
    float sk = act ? K * (start_t[ll] + em[(size_t)b * T_ + ll]) : -1e30f;
    float e_next = em[((size_t)1 * B_ + b) * T_ + ll];
    for (int s = 1; s < S_; ++s){
      float e = e_next;
      int sn = (s + 1 < S_) ? s + 1 : S_ - 1;
      e_next = em[((size_t)sn * B_ + b) * T_ + ll];
      float mk = sk;                        // own-lane anchor (no max tree)
      float ex[T_];
#pragma unroll
      for (int tt = 0; tt < T_; tt++){
        float v = bcast(sk, tt) + trc_k[tt];
        ex[tt] = __builtin_amdgcn_exp2f(v - mk);
      }
#pragma unroll
      for (int n = T_; n > 1; ){
        int h = (n + 1) >> 1;
#pragma unroll
        for (int i = 0; i < T_ / 2; i++)
          if (i + h < n) ex[i] += ex[i + h];
        n = h;
      }
      float nxt = mk + __builtin_amdgcn_logf(ex[0]) + K * e;  // logf = log2
      sk = act ? nxt : -1e30f;
    }
    float val = act ? (sk * LN2 + end_t[ll]) : -1e30f;
    float m = val;
    for (int off = 32; off; off >>= 1) m = fmaxf(m, __shfl_xor(m, off));
    float sum = __builtin_amdgcn_exp2f(K * (val - m));
    for (int off = 32; off; off >>= 1) sum += __shfl_xor(sum, off);
    if (lane == 0) res[0] = m + LN2 * __builtin_amdgcn_logf(sum);
  } else {
    int lane = t - 64;
    float acc = 0.f;
    for (int s = 1 + lane; s < S_; s += 64){
      int tp = tags[b * S_ + s - 1], tc = tags[b * S_ + s];
      acc += tr_s[tp * T_ + tc] + em[((size_t)s * B_ + b) * T_ + tc];
    }
    if (lane == 0){
      int t0 = tags[b * S_];
      acc += start_t[t0] + em[(size_t)b * T_ + t0] + end_t[tags[b * S_ + S_ - 1]];
    }
    for (int off = 32; off; off >>= 1) acc += __shfl_xor(acc, off);
    if (lane == 0) res[1] = acc;
  }
  __syncthreads();
  if (t == 0) diff[b] = res[0] - res[1];
}

// ---------------------------------------------------------------------------
__global__ __launch_bounds__(256) void final_kernel(
    const float* __restrict__ diff, float* __restrict__ out)
{
  int t = threadIdx.x;
  float v = diff[t];
  __shared__ float red[4];
  for (int off = 32; off; off >>= 1) v += __shfl_xor(v, off);
  if ((t & 63) == 0) red[t >> 6] = v;
  __syncthreads();
  if (t == 0) out[0] = red[0] + red[1] + red[2] + red[3];
}

extern "C" void kernel_launch(void* const* d_in, const int* in_sizes, int n_in,
                              void* d_out, int out_size, void* d_ws, size_t ws_size,
                              hipStream_t stream) {
  const int*   sent    = (const int*)  d_in[0];
  const int*   tags    = (const int*)  d_in[1];
  const float* tab     = (const float*)d_in[3];
  const float* w_ih_f  = (const float*)d_in[4];
  const float* w_hh_f  = (const float*)d_in[5];
  const float* b_ih_f  = (const float*)d_in[6];
  const float* b_hh_f  = (const float*)d_in[7];
  const float* w_ih_b  = (const float*)d_in[8];
  const float* w_hh_b  = (const float*)d_in[9];
  const float* b_ih_b  = (const float*)d_in[10];
  const float* b_hh_b  = (const float*)d_in[11];
  const float* w_out   = (const float*)d_in[12];
  const float* b_out   = (const float*)d_in[13];
  const float* start_t = (const float*)d_in[14];
  const float* end_t   = (const float*)d_in[15];
  const float* trans   = (const float*)d_in[16];

  // Workspace (~100 MB)
  char* ws = (char*)d_ws;
  u16*   hbuf = (u16*)ws;                          // 52,428,800 B
  float* em   = (float*)(ws + 52428800);           // 13,107,200 B
  float* diff = (float*)(ws + 65536000);           //      1,024 B
  u16*   wpad = (u16*)(ws + 65538048);             //    458,752 B
  u16*   xg   = (u16*)(ws + 65996800);             // 33,554,432 B

  prep_kernel<<<17280, 256, 0, stream>>>(sent, tab, w_ih_f, w_hh_f,
                                         w_ih_b, w_hh_b, xg, wpad);
  lstm_kernel<<<16, 896, 0, stream>>>(xg, wpad,
      b_ih_f, b_hh_f, b_ih_b, b_hh_b, hbuf);
  emis_kernel<<<512, 256, 0, stream>>>(hbuf, w_out, b_out, em);
  logznum_kernel<<<256, 128, 0, stream>>>(em, tags, start_t, end_t, trans, diff);
  final_kernel<<<1, 256, 0, stream>>>(diff, (float*)d_out);
}

// Round 8
// 1056.299 us; speedup vs baseline: 5.2328x; 5.2328x over previous
//
#include <hip/hip_runtime.h>
#include <hip/hip_bf16.h>

#define V_ 100000
#define E_ 100
#define H_ 100
#define T_ 25
#define B_ 256
#define S_ 512

using u16 = unsigned short;
using u32 = unsigned int;
using u64 = unsigned long long;
using u8  = unsigned char;
typedef __attribute__((ext_vector_type(8))) short short8;
typedef __attribute__((ext_vector_type(4))) float f32x4;

__device__ __forceinline__ u16 f2bf(float f){
  u32 x = __builtin_bit_cast(u32, f);
  u32 r = (x + 0x7FFFu + ((x >> 16) & 1u)) >> 16;  // RNE
  return (u16)r;
}
__device__ __forceinline__ float sigf(float x){
  return __builtin_amdgcn_rcpf(1.0f + __builtin_amdgcn_exp2f(-1.4426950408889634f * x));
}
__device__ __forceinline__ float tanh_fast(float x){
  return 1.0f - 2.0f * __builtin_amdgcn_rcpf(1.0f + __builtin_amdgcn_exp2f(2.8853900817779268f * x));
}
__device__ __forceinline__ float bcast(float v, int l){
  return __builtin_bit_cast(float, __builtin_amdgcn_readlane(__builtin_bit_cast(int, v), l));
}
// 256B-row XOR swizzle: byte ^= ((row&7)<<4); involution, 16B-granular
__device__ __forceinline__ int hswz(int a){ return a ^ (((a >> 8) & 7) << 4); }

__device__ __forceinline__ void gl_lds16(const void* g, void* l){
  __builtin_amdgcn_global_load_lds(
      (const __attribute__((address_space(1))) unsigned int*)g,
      (__attribute__((address_space(3))) unsigned int*)l, 16, 0, 0);
}

// f32 -> fp8 e4m3fn, RNE, flush-to-zero below 2^-6 (encoder never emits denorms)
__device__ __forceinline__ u32 f2fp8(float x){
  u32 u = __builtin_bit_cast(u32, x);
  u32 s = (u >> 24) & 0x80u;
  u32 a = u & 0x7FFFFFFFu;
  u32 r = a + 0x7FFFFu + ((a >> 20) & 1u);
  int e = (int)(r >> 23) - 120;
  if (e <= 0) return s;
  if (e > 15) e = 15;
  return s | ((u32)e << 3) | ((r >> 20) & 7u);
}

// LDS-visibility-only barrier (no vmcnt drain)
#define BAR() asm volatile("s_waitcnt lgkmcnt(0)\n\ts_barrier" ::: "memory")

// ---------------------------------------------------------------------------
// prep: build wpad_g[800][128] bf16 (GEMM B: n = dir*400+g*100+j, k zero-pad
// >=100) and wpad_h[2][448][128] bf16 (lstm A: row g*112+j', w_hh, zero-pad).
// ---------------------------------------------------------------------------
__global__ __launch_bounds__(256) void prep_kernel(
    const float* __restrict__ w_ih_f, const float* __restrict__ w_hh_f,
    const float* __restrict__ w_ih_b, const float* __restrict__ w_hh_b,
    u16* __restrict__ wpad_g, u16* __restrict__ wpad_h)
{
  int tid = blockIdx.x * 256 + threadIdx.x;
  if (tid < 102400){                       // wpad_g: 800*128
    int n = tid >> 7, k = tid & 127;
    int dir = n >= 400, np = n - 400 * dir;
    float v = 0.f;
    if (k < 100) v = (dir ? w_ih_b : w_ih_f)[np * 100 + k];
    wpad_g[tid] = f2bf(v);
  } else if (tid < 217088){                // wpad_h: 2*448*128
    int rem = tid - 102400;
    int dir = rem / 57344;
    int rr = rem % 57344;
    int row = rr >> 7, k = rr & 127;
    int g = row / 112, j = row % 112;
    float v = 0.f;
    if (j < 100 && k < 100) v = (dir ? w_hh_b : w_hh_f)[(g * 100 + j) * 100 + k];
    wpad_h[rem] = f2bf(v);
  }
}

// ---------------------------------------------------------------------------
// gx GEMM: gxp[mrow=s*256+b][800] fp8 = bias + gather(tab,sent) . wpad_g^T.
// BM=128, BN=160, K=128, 4 waves, mfma_16x16x32_bf16 (v3-proven structure).
// ---------------------------------------------------------------------------
__global__ __launch_bounds__(256) void gemm_kernel(
    const int* __restrict__ sent, const float* __restrict__ tab,
    const u16* __restrict__ wpad_g,
    const float* __restrict__ b_ih_f, const float* __restrict__ b_hh_f,
    const float* __restrict__ b_ih_b, const float* __restrict__ b_hh_b,
    u8* __restrict__ gxp)
{
  __shared__ char a_s[128 * 256];   // 32KB
  __shared__ char b_s[160 * 256];   // 40KB
  int t = threadIdx.x;
  int n0 = blockIdx.x * 160;
  int m0 = blockIdx.y * 128;

  // stage B: 40960B, 10 x 16B per thread, source pre-swizzled (rule 21)
  const char* bsrc = (const char*)wpad_g + n0 * 256;
#pragma unroll
  for (int j = 0; j < 10; j++){
    int o = j * 4096 + t * 16;
    gl_lds16(bsrc + hswz(o), b_s + o);
  }

  // stage A: 2 threads/row; gather embed row, cvt bf16, swizzled ds_write
  {
    int r = t >> 1, half = t & 1;
    int m = m0 + r, s = m >> 8, bb = m & 255;
    int idx = sent[bb * S_ + s];
    const float2* src = (const float2*)(tab + (size_t)idx * E_ + half * 50);
    int base = r * 256 + half * 100;
#pragma unroll
    for (int i = 0; i < 25; i++){
      float2 v = src[i];
      u32 p = (u32)f2bf(v.x) | ((u32)f2bf(v.y) << 16);
      *(u32*)(a_s + hswz(base + i * 4)) = p;
    }
    if (half){
#pragma unroll
      for (int j = 0; j < 7; j++)
        *(u64*)(a_s + hswz(r * 256 + 200 + j * 8)) = 0ull;
    }
  }
  __syncthreads();

  int w = t >> 6, l = t & 63;
  int cl = l & 15, ql = l >> 4;
  f32x4 acc[2][10];
#pragma unroll
  for (int mi = 0; mi < 2; mi++)
#pragma unroll
    for (int ni = 0; ni < 10; ni++) acc[mi][ni] = (f32x4){0.f, 0.f, 0.f, 0.f};

#pragma unroll
  for (int ks = 0; ks < 4; ks++){
    int cb = ks * 64 + ql * 16;
    short8 a0 = *(const short8*)(a_s + hswz((w * 32 + cl) * 256 + cb));
    short8 a1 = *(const short8*)(a_s + hswz((w * 32 + 16 + cl) * 256 + cb));
    short8 bb[10];
#pragma unroll
    for (int ni = 0; ni < 10; ni++)
      bb[ni] = *(const short8*)(b_s + hswz((ni * 16 + cl) * 256 + cb));
#pragma unroll
    for (int ni = 0; ni < 10; ni++){
      acc[0][ni] = __builtin_amdgcn_mfma_f32_16x16x32_bf16(a0, bb[ni], acc[0][ni], 0, 0, 0);
      acc[1][ni] = __builtin_amdgcn_mfma_f32_16x16x32_bf16(a1, bb[ni], acc[1][ni], 0, 0, 0);
    }
  }

  // epilogue: +bias, fp8 encode, byte store (wave-coalesced into 16B runs)
#pragma unroll
  for (int ni = 0; ni < 10; ni++){
    int col = n0 + ni * 16 + cl;
    int isb = col >= 400;
    int cn = col - 400 * isb;
    float bias = isb ? (b_ih_b[cn] + b_hh_b[cn]) : (b_ih_f[cn] + b_hh_f[cn]);
#pragma unroll
    for (int mi = 0; mi < 2; mi++){
#pragma unroll
      for (int r = 0; r < 4; r++){
        int mrow = m0 + w * 32 + mi * 16 + ql * 4 + r;
        gxp[(size_t)mrow * 800 + col] = (u8)f2fp8(acc[mi][ni][r] + bias);
      }
    }
  }
}

// ---------------------------------------------------------------------------
// LSTM recurrence, h-part only. block = (bb, dir), 448 thr = 7 waves.
// gates = decode_fp8(gx) + W_hh . h(k-1) via 16 mfma_16x16x32_bf16/wave/step.
// gx prefetched 2 steps ahead (4 dwords/lane); decode (5 ops/val, exact incl.
// subnormals: place e4m3 bits in f32 exp field, * 2^120) hoisted off the
// critical path with the next-step load issue. h dbuf in 8KB swizzled LDS.
// ---------------------------------------------------------------------------
__global__ __launch_bounds__(448, 1) void lstm_kernel(
    const u8* __restrict__ gxp, const u16* __restrict__ wpad_h,
    u16* __restrict__ hbuf)
{
  int bb = blockIdx.x, dir = blockIdx.y;
  int t = threadIdx.x, w = t >> 6, l = t & 63;
  int m = l & 15, ql = l >> 4;
  int j0 = w * 16 + ql * 4;
  bool jv = j0 < 100;
  int jl = jv ? j0 : 0;

  __shared__ __align__(16) char ha[2][4096];   // h[16][128] bf16, swizzled

  for (int i = t; i < 2048; i += 448) ((u32*)ha)[i] = 0;

  // loop-invariant W_hh fragments (64 VGPR)
  short8 bf[4][4];
  {
    const u16* wb = wpad_h + (size_t)dir * 448 * 128;
#pragma unroll
    for (int g = 0; g < 4; g++)
#pragma unroll
      for (int ks = 0; ks < 4; ks++)
        bf[g][ks] = *(const short8*)(wb + (g * 112 + w * 16 + m) * 128 + ks * 32 + ql * 8);
  }

  float c[4] = {0.f, 0.f, 0.f, 0.f};
  int s0 = dir ? (S_ - 1) : 0, sd = dir ? -1 : 1;

  // per-lane gx base (within a row): batch = bb*16+m, + dir*400 + jl
  const u8* gxbase = gxp + (size_t)(bb * 16 + m) * 800 + dir * 400 + jl;
  const long GROW = 256 * 800;     // bytes per s

  // prologue: raw(0) -> decode -> accA; raw(1) -> rB
  u32 rA[4], rB[4];
  {
    const u8* p0 = gxbase + (long)s0 * GROW;
    const u8* p1 = gxbase + (long)(s0 + sd) * GROW;
#pragma unroll
    for (int g = 0; g < 4; g++){
      rA[g] = *(const u32*)(p0 + g * 100);
      rB[g] = *(const u32*)(p1 + g * 100);
    }
  }
  f32x4 accA[4], accB[4];
#pragma unroll
  for (int g = 0; g < 4; g++)
#pragma unroll
    for (int r = 0; r < 4; r++){
      u32 b8 = rA[g] >> (8 * r);
      u32 f = ((b8 & 0x80u) << 24) | ((b8 & 0x7Fu) << 20);
      accA[g][r] = __builtin_bit_cast(float, f) * 0x1.0p120f;
    }

  u16* hout = hbuf + ((size_t)(s0 * B_ + bb * 16 + m)) * 200 + dir * 100 + j0;
  const long hstride = (long)sd * B_ * 200;
  int kcur = 0;

  __syncthreads();

  // STEP: uses ACC (= gx(k) C-init); loads raw(k+2) into RAWN; decodes
  // RAWC (= raw(k+1)) into ACCN for the next step.  KODD = kcur&1 static.
#define STEP(KODD, ACC, ACCN, RAWC, RAWN) do {                                 \
    __builtin_amdgcn_s_setprio(1);                                             \
    const char* hp_ = ha[(KODD) ^ 1];                                          \
    short8 hf_[4];                                                             \
    _Pragma("unroll")                                                          \
    for (int ks = 0; ks < 4; ks++)                                             \
      hf_[ks] = *(const short8*)(hp_ + hswz(m * 256 + ks * 64 + ql * 16));     \
    _Pragma("unroll")                                                          \
    for (int g = 0; g < 4; g++)                                                \
      _Pragma("unroll")                                                        \
      for (int ks = 0; ks < 4; ks++)                                           \
        ACC[g] = __builtin_amdgcn_mfma_f32_16x16x32_bf16(bf[g][ks], hf_[ks], ACC[g], 0, 0, 0); \
    { int kk = kcur + 2; if (kk > S_ - 1) kk = S_ - 1;                         \
      const u8* gp_ = gxbase + (long)(s0 + sd * kk) * GROW;                    \
      _Pragma("unroll")                                                        \
      for (int g = 0; g < 4; g++) RAWN[g] = *(const u32*)(gp_ + g * 100); }    \
    if (jv){                                                                   \
      u64 pk = 0;                                                              \
      _Pragma("unroll")                                                        \
      for (int r = 0; r < 4; r++){                                             \
        float gi = sigf(ACC[0][r]);                                            \
        float gf = sigf(ACC[1][r]);                                            \
        float gg = tanh_fast(ACC[2][r]);                                       \
        float go = sigf(ACC[3][r]);                                            \
        c[r] = gf * c[r] + gi * gg;                                            \
        float h = go * tanh_fast(c[r]);                                        \
        pk |= ((u64)f2bf(h)) << (16 * r);                                      \
      }                                                                        \
      *(u64*)(ha[KODD] + hswz(m * 256 + j0 * 2)) = pk;                         \
      *(u64*)hout = pk;                                                        \
    }                                                                          \
    hout += hstride;                                                           \
    __builtin_amdgcn_s_setprio(0);                                             \
    _Pragma("unroll")                                                          \
    for (int g = 0; g < 4; g++)                                                \
      _Pragma("unroll")                                                        \
      for (int r = 0; r < 4; r++){                                             \
        u32 b8 = RAWC[g] >> (8 * r);                                           \
        u32 f = ((b8 & 0x80u) << 24) | ((b8 & 0x7Fu) << 20);                   \
        ACCN[g][r] = __builtin_bit_cast(float, f) * 0x1.0p120f;                \
      }                                                                        \
    BAR();                                                                     \
    kcur++;                                                                    \
  } while (0)

  for (int it = 0; it < S_ / 2; ++it){
    STEP(0, accA, accB, rB, rA);
    STEP(1, accB, accA, rA, rB);
  }
#undef STEP
}

// ---------------------------------------------------------------------------
// emissions = [hf,hb] @ w_out^T + b_out.  w_out staged in LDS.
// ---------------------------------------------------------------------------
__global__ __launch_bounds__(256) void emis_kernel(
    const u16* __restrict__ hbuf, const float* __restrict__ w_out,
    const float* __restrict__ b_out, float* __restrict__ em)
{
  __shared__ float wsm[T_ * 200];
  int t = threadIdx.x;
  for (int i = t; i < T_ * 200; i += 256) wsm[i] = w_out[i];
  __syncthreads();

  int tid = blockIdx.x * 256 + t;   // s*B + b
  uint4 hr[25];
  const uint4* hp = (const uint4*)(hbuf + (size_t)tid * 200);
#pragma unroll
  for (int i = 0; i < 25; i++) hr[i] = hp[i];
  float* out = em + (size_t)tid * T_;
  for (int tt = 0; tt < T_; ++tt){
    const float* wr = wsm + tt * 200;
    float acc = b_out[tt];
#pragma unroll
    for (int i = 0; i < 25; i++){
      u32 q0 = hr[i].x, q1 = hr[i].y, q2 = hr[i].z, q3 = hr[i].w;
      float f;
      f = __builtin_bit_cast(float, q0 << 16);         acc += f * wr[i*8+0];
      f = __builtin_bit_cast(float, q0 & 0xFFFF0000u); acc += f * wr[i*8+1];
      f = __builtin_bit_cast(float, q1 << 16);         acc += f * wr[i*8+2];
      f = __builtin_bit_cast(float, q1 & 0xFFFF0000u); acc += f * wr[i*8+3];
      f = __builtin_bit_cast(float, q2 << 16);         acc += f * wr[i*8+4];
      f = __builtin_bit_cast(float, q2 & 0xFFFF0000u); acc += f * wr[i*8+5];
      f = __builtin_bit_cast(float, q3 << 16);         acc += f * wr[i*8+6];
      f = __builtin_bit_cast(float, q3 & 0xFFFF0000u); acc += f * wr[i*8+7];
    }
    out[tt] = acc;
  }
}

// ---------------------------------------------------------------------------
// CRF: wave 0 = logZ scan (base-2, own-lane anchor, no max tree), wave 1 =
// gold score.  diff[b] = logZ[b] - num[b].  (v7-verified.)
// ---------------------------------------------------------------------------
__global__ __launch_bounds__(128) void logznum_kernel(
    const float* __restrict__ em, const int* __restrict__ tags,
    const float* __restrict__ start_t, const float* __restrict__ end_t,
    const float* __restrict__ trans, float* __restrict__ diff)
{
  int b = blockIdx.x, t = threadIdx.x;
  __shared__ float tr_s[T_ * T_];
  __shared__ float res[2];
  for (int i = t; i < T_ * T_; i += 128) tr_s[i] = trans[i];
  __syncthreads();
  const float K  = 1.4426950408889634f;
  const float LN2 = 0.69314718055994531f;

  if (t < 64){
    int lane = t;
    bool act = lane < T_;
    int ll = act ? lane : 0;
    float trc_k[T_];
#pragma unroll
    for (int tt = 0; tt < T_; tt++) trc_k[tt] = K * tr_s[tt * T_ + ll];
    float sk = act ? K * (start_t[ll] + em[(size_t)b * T_ + ll]) : -1e30f;
    float e_next = em[((size_t)1 * B_ + b) * T_ + ll];
    for (int s = 1; s < S_; ++s){
      float e = e_next;
      int sn = (s + 1 < S_) ? s + 1 : S_ - 1;
      e_next = em[((size_t)sn * B_ + b) * T_ + ll];
      float mk = sk;
      float ex[T_];
#pragma unroll
      for (int tt = 0; tt < T_; tt++){
        float v = bcast(sk, tt) + trc_k[tt];
        ex[tt] = __builtin_amdgcn_exp2f(v - mk);
      }
#pragma unroll
      for (int n = T_; n > 1; ){
        int h = (n + 1) >> 1;
#pragma unroll
        for (int i = 0; i < T_ / 2; i++)
          if (i + h < n) ex[i] += ex[i + h];
        n = h;
      }
      float nxt = mk + __builtin_amdgcn_logf(ex[0]) + K * e;
      sk = act ? nxt : -1e30f;
    }
    float val = act ? (sk * LN2 + end_t[ll]) : -1e30f;
    float m = val;
    for (int off = 32; off; off >>= 1) m = fmaxf(m, __shfl_xor(m, off));
    float sum = __builtin_amdgcn_exp2f(K * (val - m));
    for (int off = 32; off; off >>= 1) sum += __shfl_xor(sum, off);
    if (lane == 0) res[0] = m + LN2 * __builtin_amdgcn_logf(sum);
  } else {
    int lane = t - 64;
    float acc = 0.f;
    for (int s = 1 + lane; s < S_; s += 64){
      int tp = tags[b * S_ + s - 1], tc = tags[b * S_ + s];
      acc += tr_s[tp * T_ + tc] + em[((size_t)s * B_ + b) * T_ + tc];
    }
    if (lane == 0){
      int t0 = tags[b * S_];
      acc += start_t[t0] + em[(size_t)b * T_ + t0] + end_t[tags[b * S_ + S_ - 1]];
    }
    for (int off = 32; off; off >>= 1) acc += __shfl_xor(acc, off);
    if (lane == 0) res[1] = acc;
  }
  __syncthreads();
  if (t == 0) diff[b] = res[0] - res[1];
}

// ---------------------------------------------------------------------------
__global__ __launch_bounds__(256) void final_kernel(
    const float* __restrict__ diff, float* __restrict__ out)
{
  int t = threadIdx.x;
  float v = diff[t];
  __shared__ float red[4];
  for (int off = 32; off; off >>= 1) v += __shfl_xor(v, off);
  if ((t & 63) == 0) red[t >> 6] = v;
  __syncthreads();
  if (t == 0) out[0] = red[0] + red[1] + red[2] + red[3];
}

extern "C" void kernel_launch(void* const* d_in, const int* in_sizes, int n_in,
                              void* d_out, int out_size, void* d_ws, size_t ws_size,
                              hipStream_t stream) {
  const int*   sent    = (const int*)  d_in[0];
  const int*   tags    = (const int*)  d_in[1];
  const float* tab     = (const float*)d_in[3];
  const float* w_ih_f  = (const float*)d_in[4];
  const float* w_hh_f  = (const float*)d_in[5];
  const float* b_ih_f  = (const float*)d_in[6];
  const float* b_hh_f  = (const float*)d_in[7];
  const float* w_ih_b  = (const float*)d_in[8];
  const float* w_hh_b  = (const float*)d_in[9];
  const float* b_ih_b  = (const float*)d_in[10];
  const float* b_hh_b  = (const float*)d_in[11];
  const float* w_out   = (const float*)d_in[12];
  const float* b_out   = (const float*)d_in[13];
  const float* start_t = (const float*)d_in[14];
  const float* end_t   = (const float*)d_in[15];
  const float* trans   = (const float*)d_in[16];

  // Workspace (~171 MB; v2 proved 170.4 MB works)
  char* ws = (char*)d_ws;
  u8*    gxp    = (u8*)ws;                            // 104,857,600 B
  u16*   hbuf   = (u16*)(ws + 104857600);             //  52,428,800 B
  float* em     = (float*)(ws + 157286400);           //  13,107,200 B
  float* diff   = (float*)(ws + 170393600);           //       1,024 B
  u16*   wpad_g = (u16*)(ws + 170394624);             //     204,800 B
  u16*   wpad_h = (u16*)(ws + 170599424);             //     229,376 B

  prep_kernel<<<848, 256, 0, stream>>>(w_ih_f, w_hh_f, w_ih_b, w_hh_b,
                                       wpad_g, wpad_h);
  gemm_kernel<<<dim3(5, 1024), 256, 0, stream>>>(sent, tab, wpad_g,
      b_ih_f, b_hh_f, b_ih_b, b_hh_b, gxp);
  lstm_kernel<<<dim3(16, 2), 448, 0, stream>>>(gxp, wpad_h, hbuf);
  emis_kernel<<<512, 256, 0, stream>>>(hbuf, w_out, b_out, em);
  logznum_kernel<<<256, 128, 0, stream>>>(em, tags, start_t, end_t, trans, diff);
  final_kernel<<<1, 256, 0, stream>>>(diff, (float*)d_out);
}